// Round 1
// baseline (148.359 us; speedup 1.0000x reference)
//
#include <hip/hip_runtime.h>

#define NB     2
#define SEQ    2048
#define EMBED  1024
#define HEADS  16
#define HDIM   64
#define CHUNKS 128   // s-chunks for the column-sum reduction

// ---------------------------------------------------------------------------
// Kernel 1: Sv[n][e] = sum_s values[n][s][e]   (16 MB read, the big input)
// grid = NB*CHUNKS blocks x 256 threads; each thread owns 4 consecutive cols
// (float4), sums 16 rows, then atomicAdd into the 8 KB Sv buffer.
// ---------------------------------------------------------------------------
__global__ __launch_bounds__(256) void colsum_k(const float* __restrict__ vals,
                                                float* __restrict__ Sv) {
    const int n = blockIdx.x / CHUNKS;
    const int c = blockIdx.x % CHUNKS;
    const int t = threadIdx.x;                     // float4 column index 0..255
    const float4* base = reinterpret_cast<const float4*>(vals)
                         + (size_t)n * SEQ * (EMBED / 4);
    const int ROWS = SEQ / CHUNKS;                 // 16
    const int s0 = c * ROWS;
    float4 acc = make_float4(0.f, 0.f, 0.f, 0.f);
    #pragma unroll 4
    for (int r = 0; r < ROWS; ++r) {
        float4 v = base[(size_t)(s0 + r) * (EMBED / 4) + t];
        acc.x += v.x; acc.y += v.y; acc.z += v.z; acc.w += v.w;
    }
    float* o = Sv + n * EMBED + t * 4;
    atomicAdd(o + 0, acc.x);
    atomicAdd(o + 1, acc.y);
    atomicAdd(o + 2, acc.z);
    atomicAdd(o + 3, acc.w);
}

// ---------------------------------------------------------------------------
// Kernel 2: row[n][o] = bo[o] + sum_i Wo[o][i] * Vflat[n][i]
//   where Vflat[n][h*64+d] = sum_e Wv[d][e] * Sv[n][h*64+e]
// grid = NB * (EMBED/32) blocks x 256 threads (4 waves); each wave computes
// 8 outputs via coalesced float4 reads of Wo rows + 64-lane shuffle reduce.
// Vflat (1 K floats) recomputed per block — trivial (64 FMA/elem).
// ---------------------------------------------------------------------------
__global__ __launch_bounds__(256) void matvec_k(const float* __restrict__ Sv,
                                                const float* __restrict__ Wv,
                                                const float* __restrict__ Wo,
                                                const float* __restrict__ bo,
                                                float* __restrict__ row) {
    const int n    = blockIdx.x / (EMBED / 32);
    const int oblk = blockIdx.x % (EMBED / 32);
    __shared__ float svl[EMBED];
    __shared__ float vfl[EMBED];
    const int t = threadIdx.x;

    for (int i = t; i < EMBED; i += 256) svl[i] = Sv[n * EMBED + i];
    __syncthreads();

    for (int o = t; o < EMBED; o += 256) {
        const int h = o >> 6, d = o & 63;
        const float* wr = Wv + d * HDIM;
        const float* sr = svl + h * HDIM;
        float a = 0.f;
        #pragma unroll
        for (int e = 0; e < HDIM; ++e) a += wr[e] * sr[e];
        vfl[o] = a;
    }
    __syncthreads();

    const int wave = t >> 6;
    const int lane = t & 63;
    float4 vv[4];
    #pragma unroll
    for (int it = 0; it < 4; ++it)
        vv[it] = reinterpret_cast<const float4*>(vfl)[it * 64 + lane];

    const float4* Wo4 = reinterpret_cast<const float4*>(Wo);
    #pragma unroll
    for (int j = 0; j < 8; ++j) {
        const int o = oblk * 32 + wave * 8 + j;
        float acc = 0.f;
        #pragma unroll
        for (int it = 0; it < 4; ++it) {
            float4 w4 = Wo4[(size_t)o * (EMBED / 4) + it * 64 + lane];
            acc += w4.x * vv[it].x + w4.y * vv[it].y
                 + w4.z * vv[it].z + w4.w * vv[it].w;
        }
        #pragma unroll
        for (int off = 32; off >= 1; off >>= 1)
            acc += __shfl_xor(acc, off);
        if (lane == 0) row[n * EMBED + o] = acc + bo[o];
    }
}

// ---------------------------------------------------------------------------
// Kernel 3: out[n][s][:] = row[n][:]  for all s   (16 MB write)
// grid = NB*SEQ blocks x 256 threads; one row (4 KB) per block, float4 stores.
// row lives in L2 (8 KB) after first touch.
// ---------------------------------------------------------------------------
__global__ __launch_bounds__(256) void bcast_k(const float* __restrict__ row,
                                               float4* __restrict__ out4) {
    const int b = blockIdx.x;                      // 0 .. NB*SEQ-1
    const int n = b / SEQ;
    const float4 v =
        reinterpret_cast<const float4*>(row)[n * (EMBED / 4) + threadIdx.x];
    out4[(size_t)b * (EMBED / 4) + threadIdx.x] = v;
}

// ---------------------------------------------------------------------------
extern "C" void kernel_launch(void* const* d_in, const int* in_sizes, int n_in,
                              void* d_out, int out_size, void* d_ws, size_t ws_size,
                              hipStream_t stream) {
    // setup_inputs order: values, keys, queries, mask, Wv, Wk, Wq, Wo, bo
    const float* vals = (const float*)d_in[0];
    const float* Wv   = (const float*)d_in[4];
    const float* Wo   = (const float*)d_in[7];
    const float* bo   = (const float*)d_in[8];
    float* out = (float*)d_out;

    float* Sv  = (float*)d_ws;            // NB*EMBED floats (8 KB)
    float* row = Sv + NB * EMBED;         // NB*EMBED floats (8 KB)

    // ws is poisoned to 0xAA before every call — zero the atomic accumulator.
    hipMemsetAsync(d_ws, 0, NB * EMBED * sizeof(float), stream);

    colsum_k<<<NB * CHUNKS, 256, 0, stream>>>(vals, Sv);
    matvec_k<<<NB * (EMBED / 32), 256, 0, stream>>>(Sv, Wv, Wo, bo, row);
    bcast_k <<<NB * SEQ, 256, 0, stream>>>(row, (float4*)out);
}

// Round 2
// 147.100 us; speedup vs baseline: 1.0086x; 1.0086x over previous
//
#include <hip/hip_runtime.h>

#define NB     2
#define SEQ    2048
#define EMBED  1024
#define HEADS  16
#define HDIM   64
#define CH     256            // colsum chunks per batch
#define ROWS   (SEQ / CH)     // 8 rows per chunk

// ---------------------------------------------------------------------------
// K1: part[n][c][e] = sum_{r<8} values[n][c*8+r][e]
// grid = NB*CH = 512 blocks x 256 threads (2 blocks/CU). Pure stores into ws
// (no atomics -> no memset node needed). 16 MB read, 2 MB write.
// ---------------------------------------------------------------------------
__global__ __launch_bounds__(256) void colsum_part(const float* __restrict__ vals,
                                                   float* __restrict__ part) {
    const int b = blockIdx.x;
    const int n = b / CH;
    const int c = b % CH;
    const int t = threadIdx.x;                       // float4 column 0..255
    const float4* base = reinterpret_cast<const float4*>(vals)
                       + (size_t)(n * SEQ + c * ROWS) * (EMBED / 4);
    float4 acc = make_float4(0.f, 0.f, 0.f, 0.f);
    #pragma unroll
    for (int r = 0; r < ROWS; ++r) {
        float4 v = base[(size_t)r * (EMBED / 4) + t];
        acc.x += v.x; acc.y += v.y; acc.z += v.z; acc.w += v.w;
    }
    reinterpret_cast<float4*>(part)[(size_t)(n * CH + c) * (EMBED / 4) + t] = acc;
}

// ---------------------------------------------------------------------------
// K2: row[n][o] = bo[o] + sum_i Wo[o][i] * Vflat[n][i],
//     Vflat[n][h*64+d] = sum_e Wv[d][e] * Sv[n][h*64+e],
//     Sv = reduce of part over c (done in-block from L2-resident partials).
// grid = NB * (EMBED/32) = 64 blocks x 256 threads.
// ---------------------------------------------------------------------------
__global__ __launch_bounds__(256) void matvec_k(const float* __restrict__ part,
                                                const float* __restrict__ Wv,
                                                const float* __restrict__ Wo,
                                                const float* __restrict__ bo,
                                                float* __restrict__ row) {
    const int n    = blockIdx.x >> 5;
    const int oblk = blockIdx.x & 31;
    __shared__ float svl[EMBED];
    __shared__ float vfl[EMBED];
    const int t = threadIdx.x;

    // reduce 256 partials; thread t owns float4 column t
    {
        const float4* p = reinterpret_cast<const float4*>(part)
                        + (size_t)n * CH * (EMBED / 4) + t;
        float4 acc = make_float4(0.f, 0.f, 0.f, 0.f);
        #pragma unroll 8
        for (int c = 0; c < CH; ++c) {
            float4 v = p[(size_t)c * (EMBED / 4)];
            acc.x += v.x; acc.y += v.y; acc.z += v.z; acc.w += v.w;
        }
        reinterpret_cast<float4*>(svl)[t] = acc;
    }
    __syncthreads();

    // Vflat: per-head 64x64 matvec (each thread computes 4 outputs)
    for (int o = t; o < EMBED; o += 256) {
        const int h = o >> 6, d = o & 63;
        const float* wr = Wv + d * HDIM;
        const float* sr = svl + h * HDIM;
        float a = 0.f;
        #pragma unroll
        for (int e = 0; e < HDIM; ++e) a += wr[e] * sr[e];
        vfl[o] = a;
    }
    __syncthreads();

    // Wo matvec: each wave computes 8 outputs via float4 + 64-lane reduce
    const int wave = t >> 6;
    const int lane = t & 63;
    float4 vv[4];
    #pragma unroll
    for (int it = 0; it < 4; ++it)
        vv[it] = reinterpret_cast<const float4*>(vfl)[it * 64 + lane];

    const float4* Wo4 = reinterpret_cast<const float4*>(Wo);
    #pragma unroll
    for (int j = 0; j < 8; ++j) {
        const int o = oblk * 32 + wave * 8 + j;
        float acc = 0.f;
        #pragma unroll
        for (int it = 0; it < 4; ++it) {
            float4 w4 = Wo4[(size_t)o * (EMBED / 4) + it * 64 + lane];
            acc += w4.x * vv[it].x + w4.y * vv[it].y
                 + w4.z * vv[it].z + w4.w * vv[it].w;
        }
        #pragma unroll
        for (int off = 32; off >= 1; off >>= 1)
            acc += __shfl_xor(acc, off);
        if (lane == 0) row[n * EMBED + o] = acc + bo[o];
    }
}

// ---------------------------------------------------------------------------
// K3: out[n][s][:] = row[n][:] for all s. 16 MB write.
// grid = 256 blocks x 256 threads; each block owns 16 consecutive s-rows of
// one batch; row float4 loaded once, 16 independent coalesced stores.
// ---------------------------------------------------------------------------
__global__ __launch_bounds__(256) void bcast_k(const float* __restrict__ row,
                                               float4* __restrict__ out4) {
    const int b  = blockIdx.x;            // 0..255
    const int n  = b >> 7;                // 128 blocks per batch
    const int r0 = (b & 127) * 16;        // first s-row of this block
    const float4 v =
        reinterpret_cast<const float4*>(row)[n * (EMBED / 4) + threadIdx.x];
    float4* o = out4 + (size_t)(n * SEQ + r0) * (EMBED / 4) + threadIdx.x;
    #pragma unroll
    for (int r = 0; r < 16; ++r)
        o[(size_t)r * (EMBED / 4)] = v;
}

// ---------------------------------------------------------------------------
extern "C" void kernel_launch(void* const* d_in, const int* in_sizes, int n_in,
                              void* d_out, int out_size, void* d_ws, size_t ws_size,
                              hipStream_t stream) {
    // setup_inputs order: values, keys, queries, mask, Wv, Wk, Wq, Wo, bo
    const float* vals = (const float*)d_in[0];
    const float* Wv   = (const float*)d_in[4];
    const float* Wo   = (const float*)d_in[7];
    const float* bo   = (const float*)d_in[8];
    float* out = (float*)d_out;

    float* part = (float*)d_ws;                    // NB*CH*EMBED floats (2 MB)
    float* row  = part + (size_t)NB * CH * EMBED;  // NB*EMBED floats (8 KB)

    colsum_part<<<NB * CH, 256, 0, stream>>>(vals, part);
    matvec_k<<<NB * (EMBED / 32), 256, 0, stream>>>(part, Wv, Wo, bo, row);
    bcast_k<<<256, 256, 0, stream>>>(row, (float4*)out);
}

// Round 3
// 136.367 us; speedup vs baseline: 1.0879x; 1.0787x over previous
//
#include <hip/hip_runtime.h>

#define NB     2
#define SEQ    2048
#define EMBED  1024
#define HEADS  16
#define HDIM   64
#define CH     128            // colsum partials per batch
#define ROWS   (SEQ / CH)     // 16 rows per K1 block

// ---------------------------------------------------------------------------
// K1: part[n][c][e] = sum_{r<16} values[n][c*16+r][e]
// grid = NB*CH = 256 blocks x 256 threads. 16 MB read, 1 MB write, no atomics.
// ---------------------------------------------------------------------------
__global__ __launch_bounds__(256) void colsum_part(const float* __restrict__ vals,
                                                   float* __restrict__ part) {
    const int b = blockIdx.x;
    const int n = b >> 7;                // 128 blocks per batch
    const int c = b & 127;
    const int t = threadIdx.x;           // float4 column 0..255
    const float4* base = reinterpret_cast<const float4*>(vals)
                       + (size_t)(n * SEQ + c * ROWS) * (EMBED / 4);
    float4 acc = make_float4(0.f, 0.f, 0.f, 0.f);
    #pragma unroll 8
    for (int r = 0; r < ROWS; ++r) {
        float4 v = base[(size_t)r * (EMBED / 4) + t];
        acc.x += v.x; acc.y += v.y; acc.z += v.z; acc.w += v.w;
    }
    reinterpret_cast<float4*>(part)[(size_t)b * (EMBED / 4) + t] = acc;
}

// ---------------------------------------------------------------------------
// K2: fused matvec + broadcast. grid = NB*64 = 128 blocks x 256 threads.
// Block b: batch wn = b>>6, output slice o in [s16*16, s16*16+16), s16 = b&63.
//   1) Sv = reduce of part over c (L2-resident, thread t owns float4-col t)
//   2) Vflat[h*64+d] = sum_e Wv[d][e] * Sv[h*64+e]
//   3) 16 outputs: wave j computes 4 via float4 dot + 64-lane shuffle reduce
//   4) broadcast: write these 16 columns for ALL 2048 s of batch wn
//      (out[n][s][o] = row[n][o] needs only this block's own columns).
// ---------------------------------------------------------------------------
__global__ __launch_bounds__(256) void mv_bcast(const float* __restrict__ part,
                                                const float* __restrict__ Wv,
                                                const float* __restrict__ Wo,
                                                const float* __restrict__ bo,
                                                float4* __restrict__ out4) {
    const int b   = blockIdx.x;
    const int wn  = b >> 6;              // batch
    const int s16 = b & 63;              // 16-output slice index
    const int t   = threadIdx.x;
    __shared__ float svl[EMBED];
    __shared__ float vfl[EMBED];
    __shared__ float rsl[16];

    // 1) reduce CH partials for batch wn
    {
        const float4* p = reinterpret_cast<const float4*>(part)
                        + (size_t)wn * CH * (EMBED / 4) + t;
        float4 acc = make_float4(0.f, 0.f, 0.f, 0.f);
        #pragma unroll 8
        for (int c = 0; c < CH; ++c) {
            float4 v = p[(size_t)c * (EMBED / 4)];
            acc.x += v.x; acc.y += v.y; acc.z += v.z; acc.w += v.w;
        }
        reinterpret_cast<float4*>(svl)[t] = acc;
    }
    __syncthreads();

    // 2) Vflat: per-head 64x64 matvec (each thread 4 outputs)
    for (int o = t; o < EMBED; o += 256) {
        const int h = o >> 6, d = o & 63;
        const float* wr = Wv + d * HDIM;
        const float* sr = svl + h * HDIM;
        float a = 0.f;
        #pragma unroll
        for (int e = 0; e < HDIM; ++e) a += wr[e] * sr[e];
        vfl[o] = a;
    }
    __syncthreads();

    // 3) this block's 16 outputs (wave j -> 4 outputs)
    const int wave = t >> 6;
    const int lane = t & 63;
    float4 vv[4];
    #pragma unroll
    for (int it = 0; it < 4; ++it)
        vv[it] = reinterpret_cast<const float4*>(vfl)[it * 64 + lane];

    const float4* Wo4 = reinterpret_cast<const float4*>(Wo);
    #pragma unroll
    for (int j = 0; j < 4; ++j) {
        const int o = s16 * 16 + wave * 4 + j;
        float acc = 0.f;
        #pragma unroll
        for (int it = 0; it < 4; ++it) {
            float4 w4 = Wo4[(size_t)o * (EMBED / 4) + it * 64 + lane];
            acc += w4.x * vv[it].x + w4.y * vv[it].y
                 + w4.z * vv[it].z + w4.w * vv[it].w;
        }
        #pragma unroll
        for (int off = 32; off >= 1; off >>= 1)
            acc += __shfl_xor(acc, off);
        if (lane == 0) rsl[wave * 4 + j] = acc + bo[o];
    }
    __syncthreads();

    // 4) broadcast the 16 columns over all s.
    // thread t: float4-col cs = t&3 (of this block's 4), rows s = (t>>2) + 64k.
    // A wave covers 16 consecutive s-rows x 64B contiguous -> full sectors.
    const float4 val = reinterpret_cast<const float4*>(rsl)[t & 3];
    float4* o = out4 + (size_t)wn * SEQ * (EMBED / 4) + (s16 * 4 + (t & 3))
              + (size_t)(t >> 2) * (EMBED / 4);
    #pragma unroll 8
    for (int k = 0; k < 32; ++k)
        o[(size_t)k * 64 * (EMBED / 4)] = val;
}

// ---------------------------------------------------------------------------
extern "C" void kernel_launch(void* const* d_in, const int* in_sizes, int n_in,
                              void* d_out, int out_size, void* d_ws, size_t ws_size,
                              hipStream_t stream) {
    // setup_inputs order: values, keys, queries, mask, Wv, Wk, Wq, Wo, bo
    const float* vals = (const float*)d_in[0];
    const float* Wv   = (const float*)d_in[4];
    const float* Wo   = (const float*)d_in[7];
    const float* bo   = (const float*)d_in[8];
    float* out = (float*)d_out;

    float* part = (float*)d_ws;           // NB*CH*EMBED floats (1 MB)

    colsum_part<<<NB * CH, 256, 0, stream>>>(vals, part);
    mv_bcast<<<NB * 64, 256, 0, stream>>>(part, Wv, Wo, bo, (float4*)out);
}